// Round 9
// baseline (372.378 us; speedup 1.0000x reference)
//
#include <hip/hip_runtime.h>
#include <hip/hip_bf16.h>
#include <stdint.h>

#define B_   2
#define T_   2048
#define C_   2048
#define NH_  16
#define NKV_ 4
#define D_   128
#define NREP_ 4

typedef __attribute__((ext_vector_type(8))) short bf16x8;
typedef __attribute__((ext_vector_type(4))) float f32x4;

__device__ inline short f2bs(float f) {
    __hip_bfloat16 h = __float2bfloat16(f);
    return *reinterpret_cast<short*>(&h);
}
__device__ inline float bs2f(unsigned short s) {
    __hip_bfloat16 h = *reinterpret_cast<__hip_bfloat16*>(&s);
    return __bfloat162float(h);
}

__device__ inline void gl_lds16(const __hip_bfloat16* g, __hip_bfloat16* l) {
    __builtin_amdgcn_global_load_lds(
        (const __attribute__((address_space(1))) unsigned int*)g,
        (__attribute__((address_space(3))) unsigned int*)l,
        16, 0, 0);
}

// ---------------- merged fp32 -> bf16 convert (x, Wq, Wk, Wv, Wo) ----------------
__global__ void cvt_all(const float* __restrict__ x,  const float* __restrict__ Wq,
                        const float* __restrict__ Wk, const float* __restrict__ Wv,
                        const float* __restrict__ Wo,
                        __hip_bfloat16* __restrict__ xb,
                        __hip_bfloat16* __restrict__ wcat,
                        __hip_bfloat16* __restrict__ wob) {
    int q = blockIdx.x * blockDim.x + threadIdx.x;   // quad index, total 4718592
    const float* src; __hip_bfloat16* dst; int off;
    if (q < 2097152)      { src = x;  dst = xb;             off = q; }
    else if (q < 3145728) { src = Wq; dst = wcat;           off = q - 2097152; }
    else if (q < 3407872) { src = Wk; dst = wcat + 4194304; off = q - 3145728; }
    else if (q < 3670016) { src = Wv; dst = wcat + 5242880; off = q - 3407872; }
    else                  { src = Wo; dst = wob;            off = q - 3670016; }
    int i = off * 4;
    float4 v = *reinterpret_cast<const float4*>(src + i);
    short4 o;
    o.x = f2bs(v.x); o.y = f2bs(v.y); o.z = f2bs(v.z); o.w = f2bs(v.w);
    *reinterpret_cast<short4*>(dst + i) = o;
}

// ---------------- bf16 GEMM: C = A @ B^T (m97 structure) ----------------
__device__ inline void storeC(float* p, float v) { *p = v; }
__device__ inline void storeC(__hip_bfloat16* p, float v) { *p = __float2bfloat16(v); }

template <typename OutT>
__global__ __launch_bounds__(256) void gemm_bt(const __hip_bfloat16* __restrict__ A,
                                               const __hip_bfloat16* __restrict__ Bm,
                                               OutT* __restrict__ Cm,
                                               int M, int N, int K) {
    __shared__ __hip_bfloat16 As[128 * 32];
    __shared__ __hip_bfloat16 Bs[128 * 32];
    const int tid  = threadIdx.x;
    const int lane = tid & 63;
    const int wv   = tid >> 6;
    const int m0 = blockIdx.y * 128, n0 = blockIdx.x * 128;
    const int wm = (wv >> 1) * 64, wn = (wv & 1) * 64;
    const int q16 = lane >> 4, r16 = lane & 15;

    f32x4 acc[4][4] = {};

    const int lrow = tid >> 2;
    const int lcol = (tid & 3) * 8;
    const __hip_bfloat16* aG = A  + (size_t)(m0 + lrow) * K + lcol;
    const __hip_bfloat16* bG = Bm + (size_t)(n0 + lrow) * K + lcol;
    __hip_bfloat16* aL = As + tid * 8;
    __hip_bfloat16* bL = Bs + tid * 8;

    for (int k0 = 0; k0 < K; k0 += 32) {
        __syncthreads();
        gl_lds16(aG + k0,          aL);
        gl_lds16(aG + 64 * K + k0, aL + 2048);
        gl_lds16(bG + k0,          bL);
        gl_lds16(bG + 64 * K + k0, bL + 2048);
        __syncthreads();
        bf16x8 af[4], bfr[4];
#pragma unroll
        for (int i = 0; i < 4; i++)
            af[i] = *reinterpret_cast<const bf16x8*>(As + (wm + i * 16 + r16) * 32 + q16 * 8);
#pragma unroll
        for (int j = 0; j < 4; j++)
            bfr[j] = *reinterpret_cast<const bf16x8*>(Bs + (wn + j * 16 + r16) * 32 + q16 * 8);
#pragma unroll
        for (int i = 0; i < 4; i++)
#pragma unroll
            for (int j = 0; j < 4; j++)
                acc[i][j] = __builtin_amdgcn_mfma_f32_16x16x32_bf16(af[i], bfr[j], acc[i][j], 0, 0, 0);
    }

#pragma unroll
    for (int i = 0; i < 4; i++)
#pragma unroll
        for (int j = 0; j < 4; j++)
#pragma unroll
            for (int r = 0; r < 4; r++) {
                int row = m0 + wm + i * 16 + q16 * 4 + r;
                int col = n0 + wn + j * 16 + r16;
                storeC(&Cm[(size_t)row * N + col], acc[i][j][r]);
            }
}

// ---------------- RoPE for q,k only (coalesced both ways) ----------------
__global__ void rope_qk(const __hip_bfloat16* __restrict__ y,
                        __hip_bfloat16* __restrict__ qo,
                        __hip_bfloat16* __restrict__ ko) {
    int idx = blockIdx.x * blockDim.x + threadIdx.x;   // B*T*1280 = 5,242,880
    if (idx >= (B_ * T_) * 1280) return;
    int m = idx / 1280, pc = idx % 1280;
    int b = m / T_, t = m % T_;
    int n = pc * 2;
    ushort2 uv = *reinterpret_cast<const ushort2*>(y + (size_t)m * 3072 + n);
    float e = bs2f(uv.x), od = bs2f(uv.y);

    int nn = (n < 2048) ? n : (n - 2048);
    int dloc = nn & 127;
    int p = dloc >> 1;
    float inv = __expf(-(float)p * (9.210340371976184f / 64.0f));  // 10000^(-p/64)
    float ang = (float)t * inv;
    float c = cosf(ang), s = sinf(ang);
    float re = e * c - od * s;
    float ro = e * s + od * c;
    ushort2 w;
    w.x = (unsigned short)f2bs(re);
    w.y = (unsigned short)f2bs(ro);
    if (n < 2048) {
        int h = n >> 7;
        *reinterpret_cast<ushort2*>(qo + ((size_t)(b * NH_ + h) * T_ + t) * D_ + dloc) = w;
    } else {
        int h = nn >> 7;
        *reinterpret_cast<ushort2*>(ko + ((size_t)(b * NKV_ + h) * T_ + t) * D_ + dloc) = w;
    }
}

// ---------------- V transpose: y[..,2560+g*128+d] -> vT[(b,g)][d][t], 16B stores --
__global__ void v_transpose(const __hip_bfloat16* __restrict__ y,
                            __hip_bfloat16* __restrict__ vT) {
    int idx = blockIdx.x * blockDim.x + threadIdx.x;   // 262,144
    int tc = idx & 255;
    int d  = (idx >> 8) & 127;
    int gg = (idx >> 15) & 3;
    int b  = idx >> 17;
    int t0 = tc * 8;
    const __hip_bfloat16* src = y + (size_t)(b * T_ + t0) * 3072 + 2560 + gg * 128 + d;
    ushort4 w0, w1;
    ((unsigned short*)&w0)[0] = *(const unsigned short*)(src);
    ((unsigned short*)&w0)[1] = *(const unsigned short*)(src + 3072);
    ((unsigned short*)&w0)[2] = *(const unsigned short*)(src + 2 * 3072);
    ((unsigned short*)&w0)[3] = *(const unsigned short*)(src + 3 * 3072);
    ((unsigned short*)&w1)[0] = *(const unsigned short*)(src + 4 * 3072);
    ((unsigned short*)&w1)[1] = *(const unsigned short*)(src + 5 * 3072);
    ((unsigned short*)&w1)[2] = *(const unsigned short*)(src + 6 * 3072);
    ((unsigned short*)&w1)[3] = *(const unsigned short*)(src + 7 * 3072);
    __hip_bfloat16* dst = vT + ((size_t)(b * NKV_ + gg) * D_ + d) * T_ + t0;
    *reinterpret_cast<ushort4*>(dst)     = w0;
    *reinterpret_cast<ushort4*>(dst + 4) = w1;
}

// C-layout (lane q=r16 owns s=q16*4+r, 2x 16-blocks) -> A-layout (lane needs
// P[q=r16][s=q16*8+j]) via 4-lane-group shuffles (verified r5-r8).
__device__ inline bf16x8 pf_gather(const ushort4& w0, const ushort4& w1,
                                   int q16, int r16) {
    int2 a0 = *reinterpret_cast<const int2*>(&w0);
    int2 a1 = *reinterpret_cast<const int2*>(&w1);
    int srcLo = ((q16 & 1) << 5) + r16;
    int srcHi = srcLo + 16;
    int lo0x = __shfl(a0.x, srcLo), lo0y = __shfl(a0.y, srcLo);
    int lo1x = __shfl(a1.x, srcLo), lo1y = __shfl(a1.y, srcLo);
    int hi0x = __shfl(a0.x, srcHi), hi0y = __shfl(a0.y, srcHi);
    int hi1x = __shfl(a1.x, srcHi), hi1y = __shfl(a1.y, srcHi);
    bool lw = (q16 < 2);
    int4 pk;
    pk.x = lw ? lo0x : lo1x;
    pk.y = lw ? lo0y : lo1y;
    pk.z = lw ? hi0x : hi1x;
    pk.w = lw ? hi0y : hi1y;
    return *reinterpret_cast<bf16x8*>(&pk);
}

// ---------------- flash attention: 64 q/wave (4 tiles), interleaved split-s ----
// Block = (b, g, 64-row t-tile, parity). 4 waves = 4 q-heads of group g.
// Per 32-s step: block stages K(8KB)+V(8KB) once; 8 K-frag + 8 V-frag LDS
// reads feed 64 MFMAs/wave (4 q-tiles) -> 2.7x better LDS:MFMA ratio than
// 32q/wave; per-iter MFMA issue (~310cyc) now covers the dependency chain.
// (256,2): 256-reg budget (acc 128 AGPR + bq 64 + temps); 2 blocks/CU.
__global__ __launch_bounds__(256, 2) void attn_kernel(const __hip_bfloat16* __restrict__ Q,
                                                      const __hip_bfloat16* __restrict__ Kt,
                                                      const __hip_bfloat16* __restrict__ Vt,
                                                      __hip_bfloat16* __restrict__ Op0,
                                                      __hip_bfloat16* __restrict__ Op1,
                                                      float* __restrict__ LiP) {
    __shared__ __hip_bfloat16 Ks[2][4096];   // 8 chunks x 512 shorts, x2 buffers
    __shared__ __hip_bfloat16 Vs[2][4096];

    const int lane = threadIdx.x & 63, wv = threadIdx.x >> 6;
    const int bg = blockIdx.y;                              // 0..7 : (b,g)
    const int xr = 63 - (int)blockIdx.x;                    // longest first
    const int tb = xr >> 1, half = xr & 1;                  // tb in [0,32)
    const int b = bg >> 2, g = bg & 3;
    const int h = g * 4 + wv;
    const int t0 = tb * 64;
    const int q16 = lane >> 4, r16 = lane & 15;

    const int n = 2 * (tb + 1);       // total 32-s steps for this 64-t tile

    const __hip_bfloat16* qh = Q + ((size_t)((b * NH_ + h) * T_) + t0) * D_;
    const __hip_bfloat16* kh = Kt + (size_t)(b * NKV_ + g) * T_ * D_;
    const __hip_bfloat16* vh = Vt + (size_t)(b * NKV_ + g) * D_ * T_;

    // Q as B-operand for 4 16-q tiles
    bf16x8 bq[4][4];
#pragma unroll
    for (int tile = 0; tile < 4; tile++)
#pragma unroll
        for (int kk = 0; kk < 4; kk++)
            bq[tile][kk] = *reinterpret_cast<const bf16x8*>(
                qh + (size_t)(tile * 16 + r16) * D_ + kk * 32 + q16 * 8);

    float li[4] = {0.f, 0.f, 0.f, 0.f};
    f32x4 acc[4][8];
#pragma unroll
    for (int tile = 0; tile < 4; tile++)
#pragma unroll
        for (int d = 0; d < 8; d++) acc[tile][d] = (f32x4){0.f, 0.f, 0.f, 0.f};

    const float SCL2 = 0.088388347648318447f * 1.4426950408889634f;  // (1/sqrt(D))*log2(e)

    const __hip_bfloat16* gK = kh + (size_t)((wv & 1) * 16 + r16) * D_ + q16 * 8;
    const __hip_bfloat16* gV = vh + (size_t)(((wv - 2) * 4) * 16 + r16) * T_ + q16 * 8;

#define STAGE(bufi, s0_)                                                        \
    do {                                                                        \
        if (wv < 2) {                                                           \
            const __hip_bfloat16* gp = gK + (size_t)(s0_) * D_;                 \
            __hip_bfloat16* lp = &Ks[bufi][(wv * 4) * 512] + lane * 8;          \
            gl_lds16(gp,      lp);                                              \
            gl_lds16(gp + 32, lp + 512);                                        \
            gl_lds16(gp + 64, lp + 1024);                                       \
            gl_lds16(gp + 96, lp + 1536);                                       \
        } else {                                                                \
            const __hip_bfloat16* gp = gV + (s0_);                              \
            __hip_bfloat16* lp = &Vs[bufi][((wv - 2) * 4) * 512] + lane * 8;    \
            gl_lds16(gp,                      lp);                              \
            gl_lds16(gp + (size_t)16 * T_,    lp + 512);                        \
            gl_lds16(gp + (size_t)32 * T_,    lp + 1024);                       \
            gl_lds16(gp + (size_t)48 * T_,    lp + 1536);                       \
        }                                                                       \
    } while (0)

    if (half < n) STAGE(0, half * 32);

    int j = 0;
    for (int it = half; it < n; it += 2, j++) {
        const int s0 = it * 32;
        const int cur = j & 1;
        __syncthreads();
        if (it + 2 < n) STAGE(cur ^ 1, (it + 2) * 32);

        bf16x8 akl[4], akh[4];
#pragma unroll
        for (int kk = 0; kk < 4; kk++) {
            akl[kk] = *reinterpret_cast<const bf16x8*>(&Ks[cur][kk * 512] + lane * 8);
            akh[kk] = *reinterpret_cast<const bf16x8*>(&Ks[cur][(4 + kk) * 512] + lane * 8);
        }

        bf16x8 pf[4];
#pragma unroll
        for (int tile = 0; tile < 4; tile++) {
            if (s0 <= t0 + tile * 16 + 15) {    // wave-uniform causal skip
                f32x4 sc0 = (f32x4){0.f, 0.f, 0.f, 0.f};
                f32x4 sc1 = (f32x4){0.f, 0.f, 0.f, 0.f};
#pragma unroll
                for (int kk = 0; kk < 4; kk++) {
                    sc0 = __builtin_amdgcn_mfma_f32_16x16x32_bf16(akl[kk], bq[tile][kk], sc0, 0, 0, 0);
                    sc1 = __builtin_amdgcn_mfma_f32_16x16x32_bf16(akh[kk], bq[tile][kk], sc1, 0, 0, 0);
                }
                const int tq = t0 + tile * 16 + r16;
                ushort4 w0, w1;
                float ps = 0.f;
#pragma unroll
                for (int r = 0; r < 4; r++) {
                    int s_a = s0 + q16 * 4 + r;
                    float p0 = (s_a <= tq)      ? __builtin_amdgcn_exp2f(sc0[r] * SCL2) : 0.f;
                    float p1 = (s_a + 16 <= tq) ? __builtin_amdgcn_exp2f(sc1[r] * SCL2) : 0.f;
                    ps += p0 + p1;
                    ((unsigned short*)&w0)[r] = (unsigned short)f2bs(p0);
                    ((unsigned short*)&w1)[r] = (unsigned short)f2bs(p1);
                }
                li[tile] += ps;
                pf[tile] = pf_gather(w0, w1, q16, r16);
            } else {
                int4 z = (int4){0, 0, 0, 0};
                pf[tile] = *reinterpret_cast<bf16x8*>(&z);
            }
        }

#pragma unroll
        for (int d = 0; d < 8; d++) {
            bf16x8 bv = *reinterpret_cast<const bf16x8*>(&Vs[cur][d * 512] + lane * 8);
#pragma unroll
            for (int tile = 0; tile < 4; tile++)
                acc[tile][d] = __builtin_amdgcn_mfma_f32_16x16x32_bf16(pf[tile], bv, acc[tile][d], 0, 0, 0);
        }
    }

    // reduce li across quads; every lane then has li-total for q=r16 of each tile
#pragma unroll
    for (int tile = 0; tile < 4; tile++) {
        li[tile] += __shfl_xor(li[tile], 16);
        li[tile] += __shfl_xor(li[tile], 32);
    }

    const int tileG = bg * 32 + tb;
    __hip_bfloat16* od = (half ? Op1 : Op0) + ((size_t)(tileG * 4 + wv)) * 8192;
#pragma unroll
    for (int tile = 0; tile < 4; tile++)
#pragma unroll
        for (int r = 0; r < 4; r++) {
            int qA = tile * 16 + q16 * 4 + r;
#pragma unroll
            for (int d = 0; d < 8; d++)
                od[qA * 128 + d * 16 + r16] = __float2bfloat16(acc[tile][d][r]);
        }

    // Li: [tileG][half][head][64q], q = tile*16 + r16 ; one coalesced store
    float lv = (q16 == 0) ? li[0] : (q16 == 1) ? li[1] : (q16 == 2) ? li[2] : li[3];
    float* lp = LiP + ((size_t)((tileG * 2 + half) * 4 + wv)) * 64;
    lp[q16 * 16 + r16] = lv;
#undef STAGE
}

// ---------------- combine split-s partials ----------------
__global__ void attn_combine(const __hip_bfloat16* __restrict__ O0,
                             const __hip_bfloat16* __restrict__ O1,
                             const float* __restrict__ Li,
                             __hip_bfloat16* __restrict__ Ao) {
    int idx = blockIdx.x * blockDim.x + threadIdx.x;   // 1,048,576
    int dv    = idx & 15;           // d = dv*8
    int q     = (idx >> 4) & 63;
    int hw    = (idx >> 10) & 3;
    int tileG = idx >> 12;          // bg*32 + tb
    int bg = tileG >> 5, tb = tileG & 31;
    int b = bg >> 2, g = bg & 3;

    size_t obase = ((size_t)(tileG * 4 + hw)) * 8192 + q * 128 + dv * 8;
    bf16x8 v0 = *reinterpret_cast<const bf16x8*>(O0 + obase);
    bf16x8 v1 = *reinterpret_cast<const bf16x8*>(O1 + obase);
    float li = Li[((size_t)((tileG * 2) * 4 + hw)) * 64 + q] +
               Li[((size_t)((tileG * 2 + 1) * 4 + hw)) * 64 + q];
    float inv = 1.0f / li;

    int t = tb * 64 + q;
    int h = g * 4 + hw;
    bf16x8 ov;
#pragma unroll
    for (int j = 0; j < 8; j++) {
        float s = bs2f(((const unsigned short*)&v0)[j]) + bs2f(((const unsigned short*)&v1)[j]);
        ov[j] = f2bs(s * inv);
    }
    *reinterpret_cast<bf16x8*>(Ao + ((size_t)(b * T_ + t)) * C_ + h * D_ + dv * 8) = ov;
}

// ---------------- launch ----------------
extern "C" void kernel_launch(void* const* d_in, const int* in_sizes, int n_in,
                              void* d_out, int out_size, void* d_ws, size_t ws_size,
                              hipStream_t stream) {
    const float* x  = (const float*)d_in[0];
    const float* Wq = (const float*)d_in[1];
    const float* Wk = (const float*)d_in[2];
    const float* Wv = (const float*)d_in[3];
    const float* Wo = (const float*)d_in[4];
    float* out = (float*)d_out;
    char* ws = (char*)d_ws;

    __hip_bfloat16* xb   = (__hip_bfloat16*)(ws + 0);          // 16.78 MB (dead after gemm1)
    __hip_bfloat16* wcat = (__hip_bfloat16*)(ws + 16777216);   // 12.58 MB (dead after gemm1)
    __hip_bfloat16* wob  = (__hip_bfloat16*)(ws + 29360128);   // 8.39 MB  (live til gemm2)
    __hip_bfloat16* yq   = (__hip_bfloat16*)(ws + 37748736);   // 25.17 MB (dead after rope)
    __hip_bfloat16* qatt = (__hip_bfloat16*)(ws + 62914560);   // 16.78 MB
    __hip_bfloat16* katt = (__hip_bfloat16*)(ws + 79691776);   // 4.19 MB
    __hip_bfloat16* vT   = (__hip_bfloat16*)(ws + 83886080);   // 4.19 MB
    __hip_bfloat16* aout = (__hip_bfloat16*)(ws + 88080384);   // 16.78 MB

    // split-s partials reuse dead regions during attn:
    __hip_bfloat16* Op0 = (__hip_bfloat16*)(ws + 0);           // 16.78 MB (over xb)
    __hip_bfloat16* Op1 = (__hip_bfloat16*)(ws + 37748736);    // 16.78 MB (over yq)
    float*          LiP = (float*)(ws + 54525952);             // 0.5 MB   (over yq tail)

    const int thr = 256;
    cvt_all<<<18432, thr, 0, stream>>>(x, Wq, Wk, Wv, Wo, xb, wcat, wob);

    gemm_bt<__hip_bfloat16><<<dim3(24, 32), 256, 0, stream>>>(xb, wcat, yq, 4096, 3072, 2048);

    rope_qk<<<(B_ * T_ * 1280 + thr - 1) / thr, thr, 0, stream>>>(yq, qatt, katt);
    v_transpose<<<1024, thr, 0, stream>>>(yq, vT);

    attn_kernel<<<dim3(64, 8), 256, 0, stream>>>(qatt, katt, vT, Op0, Op1, LiP);
    attn_combine<<<4096, 256, 0, stream>>>(Op0, Op1, LiP, aout);

    gemm_bt<float><<<dim3(16, 32), 256, 0, stream>>>(aout, wob, out, 4096, 2048, 2048);
}

// Round 10
// 342.956 us; speedup vs baseline: 1.0858x; 1.0858x over previous
//
#include <hip/hip_runtime.h>
#include <hip/hip_bf16.h>
#include <stdint.h>

#define B_   2
#define T_   2048
#define C_   2048
#define NH_  16
#define NKV_ 4
#define D_   128
#define NREP_ 4

typedef __attribute__((ext_vector_type(8))) short bf16x8;
typedef __attribute__((ext_vector_type(4))) float f32x4;

__device__ inline short f2bs(float f) {
    __hip_bfloat16 h = __float2bfloat16(f);
    return *reinterpret_cast<short*>(&h);
}
__device__ inline float bs2f(unsigned short s) {
    __hip_bfloat16 h = *reinterpret_cast<__hip_bfloat16*>(&s);
    return __bfloat162float(h);
}

__device__ inline void gl_lds16(const __hip_bfloat16* g, __hip_bfloat16* l) {
    __builtin_amdgcn_global_load_lds(
        (const __attribute__((address_space(1))) unsigned int*)g,
        (__attribute__((address_space(3))) unsigned int*)l,
        16, 0, 0);
}

// ---------------- merged fp32 -> bf16 convert (x, Wq, Wk, Wv, Wo) ----------------
__global__ void cvt_all(const float* __restrict__ x,  const float* __restrict__ Wq,
                        const float* __restrict__ Wk, const float* __restrict__ Wv,
                        const float* __restrict__ Wo,
                        __hip_bfloat16* __restrict__ xb,
                        __hip_bfloat16* __restrict__ wcat,
                        __hip_bfloat16* __restrict__ wob) {
    int q = blockIdx.x * blockDim.x + threadIdx.x;   // quad index, total 4718592
    const float* src; __hip_bfloat16* dst; int off;
    if (q < 2097152)      { src = x;  dst = xb;             off = q; }
    else if (q < 3145728) { src = Wq; dst = wcat;           off = q - 2097152; }
    else if (q < 3407872) { src = Wk; dst = wcat + 4194304; off = q - 3145728; }
    else if (q < 3670016) { src = Wv; dst = wcat + 5242880; off = q - 3407872; }
    else                  { src = Wo; dst = wob;            off = q - 3670016; }
    int i = off * 4;
    float4 v = *reinterpret_cast<const float4*>(src + i);
    short4 o;
    o.x = f2bs(v.x); o.y = f2bs(v.y); o.z = f2bs(v.z); o.w = f2bs(v.w);
    *reinterpret_cast<short4*>(dst + i) = o;
}

// ---------------- bf16 GEMM: C = A @ B^T (m97 structure) ----------------
__device__ inline void storeC(float* p, float v) { *p = v; }
__device__ inline void storeC(__hip_bfloat16* p, float v) { *p = __float2bfloat16(v); }

template <typename OutT>
__global__ __launch_bounds__(256) void gemm_bt(const __hip_bfloat16* __restrict__ A,
                                               const __hip_bfloat16* __restrict__ Bm,
                                               OutT* __restrict__ Cm,
                                               int M, int N, int K) {
    __shared__ __hip_bfloat16 As[128 * 32];
    __shared__ __hip_bfloat16 Bs[128 * 32];
    const int tid  = threadIdx.x;
    const int lane = tid & 63;
    const int wv   = tid >> 6;
    const int m0 = blockIdx.y * 128, n0 = blockIdx.x * 128;
    const int wm = (wv >> 1) * 64, wn = (wv & 1) * 64;
    const int q16 = lane >> 4, r16 = lane & 15;

    f32x4 acc[4][4] = {};

    const int lrow = tid >> 2;
    const int lcol = (tid & 3) * 8;
    const __hip_bfloat16* aG = A  + (size_t)(m0 + lrow) * K + lcol;
    const __hip_bfloat16* bG = Bm + (size_t)(n0 + lrow) * K + lcol;
    __hip_bfloat16* aL = As + tid * 8;
    __hip_bfloat16* bL = Bs + tid * 8;

    for (int k0 = 0; k0 < K; k0 += 32) {
        __syncthreads();
        gl_lds16(aG + k0,          aL);
        gl_lds16(aG + 64 * K + k0, aL + 2048);
        gl_lds16(bG + k0,          bL);
        gl_lds16(bG + 64 * K + k0, bL + 2048);
        __syncthreads();
        bf16x8 af[4], bfr[4];
#pragma unroll
        for (int i = 0; i < 4; i++)
            af[i] = *reinterpret_cast<const bf16x8*>(As + (wm + i * 16 + r16) * 32 + q16 * 8);
#pragma unroll
        for (int j = 0; j < 4; j++)
            bfr[j] = *reinterpret_cast<const bf16x8*>(Bs + (wn + j * 16 + r16) * 32 + q16 * 8);
#pragma unroll
        for (int i = 0; i < 4; i++)
#pragma unroll
            for (int j = 0; j < 4; j++)
                acc[i][j] = __builtin_amdgcn_mfma_f32_16x16x32_bf16(af[i], bfr[j], acc[i][j], 0, 0, 0);
    }

#pragma unroll
    for (int i = 0; i < 4; i++)
#pragma unroll
        for (int j = 0; j < 4; j++)
#pragma unroll
            for (int r = 0; r < 4; r++) {
                int row = m0 + wm + i * 16 + q16 * 4 + r;
                int col = n0 + wn + j * 16 + r16;
                storeC(&Cm[(size_t)row * N + col], acc[i][j][r]);
            }
}

// ---------------- RoPE for q,k only (coalesced both ways) ----------------
__global__ void rope_qk(const __hip_bfloat16* __restrict__ y,
                        __hip_bfloat16* __restrict__ qo,
                        __hip_bfloat16* __restrict__ ko) {
    int idx = blockIdx.x * blockDim.x + threadIdx.x;   // B*T*1280 = 5,242,880
    if (idx >= (B_ * T_) * 1280) return;
    int m = idx / 1280, pc = idx % 1280;
    int b = m / T_, t = m % T_;
    int n = pc * 2;
    ushort2 uv = *reinterpret_cast<const ushort2*>(y + (size_t)m * 3072 + n);
    float e = bs2f(uv.x), od = bs2f(uv.y);

    int nn = (n < 2048) ? n : (n - 2048);
    int dloc = nn & 127;
    int p = dloc >> 1;
    float inv = __expf(-(float)p * (9.210340371976184f / 64.0f));  // 10000^(-p/64)
    float ang = (float)t * inv;
    float c = cosf(ang), s = sinf(ang);
    float re = e * c - od * s;
    float ro = e * s + od * c;
    ushort2 w;
    w.x = (unsigned short)f2bs(re);
    w.y = (unsigned short)f2bs(ro);
    if (n < 2048) {
        int h = n >> 7;
        *reinterpret_cast<ushort2*>(qo + ((size_t)(b * NH_ + h) * T_ + t) * D_ + dloc) = w;
    } else {
        int h = nn >> 7;
        *reinterpret_cast<ushort2*>(ko + ((size_t)(b * NKV_ + h) * T_ + t) * D_ + dloc) = w;
    }
}

// ---------------- V transpose: y[..,2560+g*128+d] -> vT[(b,g)][d][t], 16B stores --
__global__ void v_transpose(const __hip_bfloat16* __restrict__ y,
                            __hip_bfloat16* __restrict__ vT) {
    int idx = blockIdx.x * blockDim.x + threadIdx.x;   // 262,144
    int tc = idx & 255;
    int d  = (idx >> 8) & 127;
    int gg = (idx >> 15) & 3;
    int b  = idx >> 17;
    int t0 = tc * 8;
    const __hip_bfloat16* src = y + (size_t)(b * T_ + t0) * 3072 + 2560 + gg * 128 + d;
    ushort4 w0, w1;
    ((unsigned short*)&w0)[0] = *(const unsigned short*)(src);
    ((unsigned short*)&w0)[1] = *(const unsigned short*)(src + 3072);
    ((unsigned short*)&w0)[2] = *(const unsigned short*)(src + 2 * 3072);
    ((unsigned short*)&w0)[3] = *(const unsigned short*)(src + 3 * 3072);
    ((unsigned short*)&w1)[0] = *(const unsigned short*)(src + 4 * 3072);
    ((unsigned short*)&w1)[1] = *(const unsigned short*)(src + 5 * 3072);
    ((unsigned short*)&w1)[2] = *(const unsigned short*)(src + 6 * 3072);
    ((unsigned short*)&w1)[3] = *(const unsigned short*)(src + 7 * 3072);
    __hip_bfloat16* dst = vT + ((size_t)(b * NKV_ + gg) * D_ + d) * T_ + t0;
    *reinterpret_cast<ushort4*>(dst)     = w0;
    *reinterpret_cast<ushort4*>(dst + 4) = w1;
}

// C-layout (lane q=r16 owns s=q16*4+r, 2x 16-blocks) -> A-layout (lane needs
// P[q=r16][s=q16*8+j]) via 4-lane-group shuffles (verified r5-r9).
__device__ inline bf16x8 pf_gather(const ushort4& w0, const ushort4& w1,
                                   int q16, int r16) {
    int2 a0 = *reinterpret_cast<const int2*>(&w0);
    int2 a1 = *reinterpret_cast<const int2*>(&w1);
    int srcLo = ((q16 & 1) << 5) + r16;
    int srcHi = srcLo + 16;
    int lo0x = __shfl(a0.x, srcLo), lo0y = __shfl(a0.y, srcLo);
    int lo1x = __shfl(a1.x, srcLo), lo1y = __shfl(a1.y, srcLo);
    int hi0x = __shfl(a0.x, srcHi), hi0y = __shfl(a0.y, srcHi);
    int hi1x = __shfl(a1.x, srcHi), hi1y = __shfl(a1.y, srcHi);
    bool lw = (q16 < 2);
    int4 pk;
    pk.x = lw ? lo0x : lo1x;
    pk.y = lw ? lo0y : lo1y;
    pk.z = lw ? hi0x : hi1x;
    pk.w = lw ? hi0y : hi1y;
    return *reinterpret_cast<bf16x8*>(&pk);
}

// ---------------- flash attention: 32q/wave, split-s, UNIFORM WORK PAIRING ----
// Block = (b, g) x paired half-tiles {bx, 127-bx}, processed as 2 sequential
// phases. Every block does ~33 total 32-s steps (sum is constant) -> zero
// causal-tail imbalance: 512 uniform blocks, 2/CU, all resident, all finish
// together (r8's imbalanced 1024-block version averaged only ~5 waves/CU).
// Per phase = r8 config: 4 waves = 4 q-heads of group g, 2x16q tiles/wave,
// K(8KB)+V(8KB) staged once per 32-s step, interleaved split-s parity,
// m=0 softmax (exact combine o=(o0+o1)/(l0+l1)), pf_gather shuffles for
// P C->A layout. (256,3): r6/r7 showed (256,4) spills (144 regs needed).
__global__ __launch_bounds__(256, 3) void attn_kernel(const __hip_bfloat16* __restrict__ Q,
                                                      const __hip_bfloat16* __restrict__ Kt,
                                                      const __hip_bfloat16* __restrict__ Vt,
                                                      __hip_bfloat16* __restrict__ Op0,
                                                      __hip_bfloat16* __restrict__ Op1,
                                                      float* __restrict__ LiP) {
    __shared__ __hip_bfloat16 Ks[2][4096];   // 8 chunks x 512 shorts, x2 buffers
    __shared__ __hip_bfloat16 Vs[2][4096];

    const int lane = threadIdx.x & 63, wv = threadIdx.x >> 6;
    const int bg = blockIdx.y;                              // 0..7 : (b,g)
    const int bx = (int)blockIdx.x;                         // 0..63
    const int b = bg >> 2, g = bg & 3;
    const int h = g * 4 + wv;
    const int q16 = lane >> 4, r16 = lane & 15;

    const __hip_bfloat16* kh = Kt + (size_t)(b * NKV_ + g) * T_ * D_;
    const __hip_bfloat16* vh = Vt + (size_t)(b * NKV_ + g) * D_ * T_;
    const __hip_bfloat16* gK = kh + (size_t)((wv & 1) * 16 + r16) * D_ + q16 * 8;
    const __hip_bfloat16* gV = vh + (size_t)(((wv - 2) * 4) * 16 + r16) * T_ + q16 * 8;

    const float SCL2 = 0.088388347648318447f * 1.4426950408889634f;  // (1/sqrt(D))*log2(e)

#define STAGE(bufi, s0_)                                                        \
    do {                                                                        \
        if (wv < 2) {                                                           \
            const __hip_bfloat16* gp = gK + (size_t)(s0_) * D_;                 \
            __hip_bfloat16* lp = &Ks[bufi][(wv * 4) * 512] + lane * 8;          \
            gl_lds16(gp,      lp);                                              \
            gl_lds16(gp + 32, lp + 512);                                        \
            gl_lds16(gp + 64, lp + 1024);                                       \
            gl_lds16(gp + 96, lp + 1536);                                       \
        } else {                                                                \
            const __hip_bfloat16* gp = gV + (s0_);                              \
            __hip_bfloat16* lp = &Vs[bufi][((wv - 2) * 4) * 512] + lane * 8;    \
            gl_lds16(gp,                      lp);                              \
            gl_lds16(gp + (size_t)16 * T_,    lp + 512);                        \
            gl_lds16(gp + (size_t)32 * T_,    lp + 1024);                       \
            gl_lds16(gp + (size_t)48 * T_,    lp + 1536);                       \
        }                                                                       \
    } while (0)

    for (int ph = 0; ph < 2; ph++) {
        const int xr = ph ? (127 - bx) : bx;
        const int tb = xr >> 1, half = xr & 1;
        const int t0 = tb * 32;
        const int n = tb + 1;            // total 32-s steps for this tile

        const __hip_bfloat16* qh = Q + ((size_t)((b * NH_ + h) * T_) + t0) * D_;
        bf16x8 bqA[4], bqB[4];
#pragma unroll
        for (int kk = 0; kk < 4; kk++) {
            bqA[kk] = *reinterpret_cast<const bf16x8*>(qh + (size_t)r16 * D_ + kk * 32 + q16 * 8);
            bqB[kk] = *reinterpret_cast<const bf16x8*>(qh + (size_t)(16 + r16) * D_ + kk * 32 + q16 * 8);
        }

        float liA = 0.f, liB = 0.f;
        f32x4 oA[8], oB[8];
#pragma unroll
        for (int d = 0; d < 8; d++) {
            oA[d] = (f32x4){0.f, 0.f, 0.f, 0.f};
            oB[d] = (f32x4){0.f, 0.f, 0.f, 0.f};
        }

        const int tqA = t0 + r16;
        const int tqB = t0 + 16 + r16;

        if (half < n) STAGE(0, half * 32);

        int j = 0;
        for (int it = half; it < n; it += 2, j++) {
            const int s0 = it * 32;
            const int cur = j & 1;
            __syncthreads();
            if (it + 2 < n) STAGE(cur ^ 1, (it + 2) * 32);

            f32x4 sc0A = (f32x4){0.f, 0.f, 0.f, 0.f};
            f32x4 sc1A = (f32x4){0.f, 0.f, 0.f, 0.f};
            f32x4 sc0B = (f32x4){0.f, 0.f, 0.f, 0.f};
            f32x4 sc1B = (f32x4){0.f, 0.f, 0.f, 0.f};
            {
                bf16x8 ak[4];
#pragma unroll
                for (int kk = 0; kk < 4; kk++)
                    ak[kk] = *reinterpret_cast<const bf16x8*>(&Ks[cur][kk * 512] + lane * 8);
#pragma unroll
                for (int kk = 0; kk < 4; kk++) {
                    sc0A = __builtin_amdgcn_mfma_f32_16x16x32_bf16(ak[kk], bqA[kk], sc0A, 0, 0, 0);
                    sc0B = __builtin_amdgcn_mfma_f32_16x16x32_bf16(ak[kk], bqB[kk], sc0B, 0, 0, 0);
                }
#pragma unroll
                for (int kk = 0; kk < 4; kk++)
                    ak[kk] = *reinterpret_cast<const bf16x8*>(&Ks[cur][(4 + kk) * 512] + lane * 8);
#pragma unroll
                for (int kk = 0; kk < 4; kk++) {
                    sc1A = __builtin_amdgcn_mfma_f32_16x16x32_bf16(ak[kk], bqA[kk], sc1A, 0, 0, 0);
                    sc1B = __builtin_amdgcn_mfma_f32_16x16x32_bf16(ak[kk], bqB[kk], sc1B, 0, 0, 0);
                }
            }

            ushort4 w0A, w1A, w0B, w1B;
            float psA = 0.f, psB = 0.f;
#pragma unroll
            for (int r = 0; r < 4; r++) {
                int s_a = s0 + q16 * 4 + r;
                float pa0 = (s_a <= tqA)      ? __builtin_amdgcn_exp2f(sc0A[r] * SCL2) : 0.f;
                float pa1 = (s_a + 16 <= tqA) ? __builtin_amdgcn_exp2f(sc1A[r] * SCL2) : 0.f;
                float pb0 = (s_a <= tqB)      ? __builtin_amdgcn_exp2f(sc0B[r] * SCL2) : 0.f;
                float pb1 = (s_a + 16 <= tqB) ? __builtin_amdgcn_exp2f(sc1B[r] * SCL2) : 0.f;
                psA += pa0 + pa1;
                psB += pb0 + pb1;
                ((unsigned short*)&w0A)[r] = (unsigned short)f2bs(pa0);
                ((unsigned short*)&w1A)[r] = (unsigned short)f2bs(pa1);
                ((unsigned short*)&w0B)[r] = (unsigned short)f2bs(pb0);
                ((unsigned short*)&w1B)[r] = (unsigned short)f2bs(pb1);
            }
            liA += psA;
            liB += psB;

            bf16x8 pfA = pf_gather(w0A, w1A, q16, r16);
            bf16x8 pfB = pf_gather(w0B, w1B, q16, r16);

#pragma unroll
            for (int d = 0; d < 8; d++) {
                bf16x8 bv = *reinterpret_cast<const bf16x8*>(&Vs[cur][d * 512] + lane * 8);
                oA[d] = __builtin_amdgcn_mfma_f32_16x16x32_bf16(pfA, bv, oA[d], 0, 0, 0);
                oB[d] = __builtin_amdgcn_mfma_f32_16x16x32_bf16(pfB, bv, oB[d], 0, 0, 0);
            }
        }

        // reduce li across quads; lane r16 then holds totals
        liA += __shfl_xor(liA, 16);
        liA += __shfl_xor(liA, 32);
        liB += __shfl_xor(liB, 16);
        liB += __shfl_xor(liB, 32);

        const int tile = bg * 64 + tb;
        __hip_bfloat16* od = (half ? Op1 : Op0) + ((size_t)(tile * 4 + wv)) * 4096;
#pragma unroll
        for (int r = 0; r < 4; r++) {
            int qA = q16 * 4 + r;
#pragma unroll
            for (int d = 0; d < 8; d++) {
                od[qA * 128 + d * 16 + r16]        = __float2bfloat16(oA[d][r]);
                od[(qA + 16) * 128 + d * 16 + r16] = __float2bfloat16(oB[d][r]);
            }
        }
        float* lp = LiP + ((size_t)(tile * 2 + half)) * 128 + wv * 32;
        if (q16 == 0) lp[r16] = liA;
        if (q16 == 1) lp[16 + r16] = liB;

        __syncthreads();   // LDS quiesce before next phase's prologue STAGE
    }
#undef STAGE
}

// ---------------- combine split-s partials ----------------
__global__ void attn_combine(const __hip_bfloat16* __restrict__ O0,
                             const __hip_bfloat16* __restrict__ O1,
                             const float* __restrict__ Li,
                             __hip_bfloat16* __restrict__ Ao) {
    int idx = blockIdx.x * blockDim.x + threadIdx.x;   // 1,048,576 total
    int dv   = idx & 15;            // d = dv*8
    int q    = (idx >> 4) & 31;
    int hw   = (idx >> 9) & 3;
    int tile = idx >> 11;           // bg*64 + tb
    int bg = tile >> 6, tb = tile & 63;
    int b = bg >> 2, g = bg & 3;

    size_t obase = ((size_t)(tile * 4 + hw)) * 4096 + q * 128 + dv * 8;
    bf16x8 v0 = *reinterpret_cast<const bf16x8*>(O0 + obase);
    bf16x8 v1 = *reinterpret_cast<const bf16x8*>(O1 + obase);
    float li = Li[(size_t)(tile * 2) * 128 + hw * 32 + q] +
               Li[(size_t)(tile * 2 + 1) * 128 + hw * 32 + q];
    float inv = 1.0f / li;

    int t = tb * 32 + q;
    int h = g * 4 + hw;
    bf16x8 ov;
#pragma unroll
    for (int j = 0; j < 8; j++) {
        float s = bs2f(((const unsigned short*)&v0)[j]) + bs2f(((const unsigned short*)&v1)[j]);
        ov[j] = f2bs(s * inv);
    }
    *reinterpret_cast<bf16x8*>(Ao + ((size_t)(b * T_ + t)) * C_ + h * D_ + dv * 8) = ov;
}

// ---------------- launch ----------------
extern "C" void kernel_launch(void* const* d_in, const int* in_sizes, int n_in,
                              void* d_out, int out_size, void* d_ws, size_t ws_size,
                              hipStream_t stream) {
    const float* x  = (const float*)d_in[0];
    const float* Wq = (const float*)d_in[1];
    const float* Wk = (const float*)d_in[2];
    const float* Wv = (const float*)d_in[3];
    const float* Wo = (const float*)d_in[4];
    float* out = (float*)d_out;
    char* ws = (char*)d_ws;

    __hip_bfloat16* xb   = (__hip_bfloat16*)(ws + 0);          // 16.78 MB (dead after gemm1)
    __hip_bfloat16* wcat = (__hip_bfloat16*)(ws + 16777216);   // 12.58 MB (dead after gemm1)
    __hip_bfloat16* wob  = (__hip_bfloat16*)(ws + 29360128);   // 8.39 MB  (live til gemm2)
    __hip_bfloat16* yq   = (__hip_bfloat16*)(ws + 37748736);   // 25.17 MB (dead after rope)
    __hip_bfloat16* qatt = (__hip_bfloat16*)(ws + 62914560);   // 16.78 MB
    __hip_bfloat16* katt = (__hip_bfloat16*)(ws + 79691776);   // 4.19 MB
    __hip_bfloat16* vT   = (__hip_bfloat16*)(ws + 83886080);   // 4.19 MB
    __hip_bfloat16* aout = (__hip_bfloat16*)(ws + 88080384);   // 16.78 MB

    // split-s partials reuse dead regions during attn:
    __hip_bfloat16* Op0 = (__hip_bfloat16*)(ws + 0);           // 16.78 MB (over xb)
    __hip_bfloat16* Op1 = (__hip_bfloat16*)(ws + 37748736);    // 16.78 MB (over yq)
    float*          LiP = (float*)(ws + 54525952);             // 0.5 MB   (over yq tail)

    const int thr = 256;
    cvt_all<<<18432, thr, 0, stream>>>(x, Wq, Wk, Wv, Wo, xb, wcat, wob);

    gemm_bt<__hip_bfloat16><<<dim3(24, 32), 256, 0, stream>>>(xb, wcat, yq, 4096, 3072, 2048);

    rope_qk<<<(B_ * T_ * 1280 + thr - 1) / thr, thr, 0, stream>>>(yq, qatt, katt);
    v_transpose<<<1024, thr, 0, stream>>>(yq, vT);

    attn_kernel<<<dim3(64, 8), 256, 0, stream>>>(qatt, katt, vT, Op0, Op1, LiP);
    attn_combine<<<4096, 256, 0, stream>>>(Op0, Op1, LiP, aout);

    gemm_bt<float><<<dim3(16, 32), 256, 0, stream>>>(aout, wob, out, 4096, 2048, 2048);
}